// Round 6
// baseline (126.484 us; speedup 1.0000x reference)
//
#include <hip/hip_runtime.h>

#define NE     100000
#define NR     64
#define DIM    16
#define NHOP   2
#define NMEM   32
#define NNODES 16384

// i8 R-table in LDS, transposed: rt[r*RELP + e*16 + d] = quant(R[r][d][e]).
// Column read (16 d for one e) = 2x ds_read_b64 at +0/+8.
// RELP=272 = 68 dwords -> relation r shifts banks by 4r mod 32: the 4 lane
// groups (random distinct relations) land on decorrelated banks; within a
// group lanes e and e+8 alias 2-way (free, m136).
#define RELP   272
#define WPITCH 20     // W staging pitch in floats
#define WSMAX  (DIM * WPITCH)   // offset of the 4 per-wave max slots

static __device__ __forceinline__ int sdot4(unsigned a, unsigned b, int c) {
#if __has_builtin(__builtin_amdgcn_sdot4)
    return __builtin_amdgcn_sdot4((int)a, (int)b, c, false);
#else
    #pragma unroll
    for (int k = 0; k < 4; ++k) {
        int xa = (int)((a >> (8 * k)) & 0xffu); xa = (xa ^ 0x80) - 0x80;
        int xb = (int)((b >> (8 * k)) & 0xffu); xb = (xb ^ 0x80) - 0x80;
        c += xa * xb;
    }
    return c;
#endif
}

// Sum across 16 contiguous lanes, broadcast. Pure DPP (VALU pipe).
static __device__ __forceinline__ float dpp_sum16(float v) {
    union { int i; float f; } a, b;
    a.f = v;
    b.i = __builtin_amdgcn_update_dpp(0, a.i, 0xB1,  0xf, 0xf, true); a.f += b.f; // quad_perm [1,0,3,2]
    b.i = __builtin_amdgcn_update_dpp(0, a.i, 0x4E,  0xf, 0xf, true); a.f += b.f; // quad_perm [2,3,0,1]
    b.i = __builtin_amdgcn_update_dpp(0, a.i, 0x124, 0xf, 0xf, true); a.f += b.f; // row_ror:4
    b.i = __builtin_amdgcn_update_dpp(0, a.i, 0x128, 0xf, 0xf, true); a.f += b.f; // row_ror:8
    return a.f;
}
// Max across 16 contiguous lanes, broadcast.
static __device__ __forceinline__ float dpp_max16(float v) {
    union { int i; float f; } a, b;
    a.f = v;
    b.i = __builtin_amdgcn_update_dpp(0, a.i, 0xB1,  0xf, 0xf, true); a.f = fmaxf(a.f, b.f);
    b.i = __builtin_amdgcn_update_dpp(0, a.i, 0x4E,  0xf, 0xf, true); a.f = fmaxf(a.f, b.f);
    b.i = __builtin_amdgcn_update_dpp(0, a.i, 0x124, 0xf, 0xf, true); a.f = fmaxf(a.f, b.f);
    b.i = __builtin_amdgcn_update_dpp(0, a.i, 0x128, 0xf, 0xf, true); a.f = fmaxf(a.f, b.f);
    return a.f;
}

// Wave-uniform broadcast into an SGPR.
static __device__ __forceinline__ float bcast(float v, int l) {
    return __int_as_float(__builtin_amdgcn_readlane(__float_as_int(v), l));
}

extern "C" __global__ void __launch_bounds__(256, 6)
ripple_kernel(const int* __restrict__ nodes,
              const int* __restrict__ mh,
              const int* __restrict__ mr,
              const int* __restrict__ mt,
              const float* __restrict__ ent,
              const float* __restrict__ rel,
              const float* __restrict__ W,
              float* __restrict__ out)
{
    __shared__ __align__(16) char  rt[NR * RELP];        // 17408 B
    __shared__ __align__(16) float ws[WSMAX + 4];        // W rows + 4 wave-max slots

    const int tid = threadIdx.x;

    // ---- Pass 1: block absmax of rel (contiguous float4 reads; NO live buffer) ----
    {
        const float4* rel4 = (const float4*)rel;
        float m = 0.f;
        #pragma unroll
        for (int i = 0; i < 16; ++i) {
            float4 v = rel4[i * 256 + tid];
            m = fmaxf(m, fmaxf(fmaxf(fabsf(v.x), fabsf(v.y)),
                               fmaxf(fabsf(v.z), fabsf(v.w))));
        }
        #pragma unroll
        for (int off = 32; off; off >>= 1) m = fmaxf(m, __shfl_xor(m, off));
        if ((tid & 63) == 0) ws[WSMAX + (tid >> 6)] = m;
        ws[(tid >> 4) * WPITCH + (tid & 15)] = W[tid];   // stage W rows
    }
    __syncthreads();

    const float smax = fmaxf(fmaxf(fmaxf(ws[WSMAX], ws[WSMAX + 1]),
                                   fmaxf(ws[WSMAX + 2], ws[WSMAX + 3])), 1e-30f);
    const float rs = smax * (1.f / 127.f);   // i8 -> R dequant scale

    // ---- Pass 2: reload (L2-hot 64 KB), quantize, pack -> b32 LDS stores ----
    // Task T: r=T>>6, e=(T>>2)&15, d0=(T&3)*4. Thread loads R[r][d0..d0+3][e]
    // (4 dwords, stride 64 B; per wave = 4 full cache lines per instruction).
    {
        const float qs = 127.f / smax;
        #pragma unroll
        for (int i = 0; i < 16; ++i) {
            int T = i * 256 + tid;
            int r = T >> 6, e = (T >> 2) & 15, d0 = (T & 3) << 2;
            const float* p = rel + r * 256 + d0 * 16 + e;
            float a = p[0], b = p[16], c = p[32], d = p[48];
            int qa = (int)rintf(a * qs), qb = (int)rintf(b * qs);
            int qc = (int)rintf(c * qs), qd = (int)rintf(d * qs);
            qa = qa < -127 ? -127 : (qa > 127 ? 127 : qa);
            qb = qb < -127 ? -127 : (qb > 127 ? 127 : qb);
            qc = qc < -127 ? -127 : (qc > 127 ? 127 : qc);
            qd = qd < -127 ? -127 : (qd > 127 ? 127 : qd);
            unsigned pk = ((unsigned)qa & 0xffu)        | (((unsigned)qb & 0xffu) << 8)
                        | (((unsigned)qc & 0xffu) << 16) | (((unsigned)qd & 0xffu) << 24);
            *(unsigned*)&rt[r * RELP + e * 16 + d0] = pk;
        }
    }
    __syncthreads();

    const int lane = tid & 63;
    const int wid  = tid >> 6;
    const int g    = lane >> 4;   // mem-group 0..3 -> owns mems [8g, 8g+8)
    const int e    = lane & 15;   // dim index
    const int n    = blockIdx.x * 4 + wid;

    float item    = ent[nodes[n] * DIM + e];
    float out_acc = 0.f;

    #pragma unroll
    for (int hop = 0; hop < NHOP; ++hop) {
        // per-wave item quantization (i8; scale via DPP max over 16 dims)
        const float mx = fmaxf(dpp_max16(fabsf(item)), 1e-30f);
        int q8 = (int)rintf(item * (127.f / mx));
        q8 = q8 < -127 ? -127 : (q8 > 127 ? 127 : q8);
        unsigned ip[4];
        #pragma unroll
        for (int j = 0; j < 4; ++j) {
            unsigned b0 = (unsigned)__builtin_amdgcn_readlane(q8, 4 * j + 0) & 0xffu;
            unsigned b1 = (unsigned)__builtin_amdgcn_readlane(q8, 4 * j + 1) & 0xffu;
            unsigned b2 = (unsigned)__builtin_amdgcn_readlane(q8, 4 * j + 2) & 0xffu;
            unsigned b3 = (unsigned)__builtin_amdgcn_readlane(q8, 4 * j + 3) & 0xffu;
            ip[j] = b0 | (b1 << 8) | (b2 << 16) | (b3 << 24);
        }
        const float cq = rs * mx * (1.f / 127.f);  // int-dot -> score factor

        // contiguous per-lane index loads: 6 x int4
        const int ibase = hop * (NNODES * NMEM) + n * NMEM + g * 8;
        int hi[8], ri[8], ti[8];
        {
            const int4* p;
            p = (const int4*)(mh + ibase); *(int4*)&hi[0] = p[0]; *(int4*)&hi[4] = p[1];
            p = (const int4*)(mr + ibase); *(int4*)&ri[0] = p[0]; *(int4*)&ri[4] = p[1];
            p = (const int4*)(mt + ibase); *(int4*)&ti[0] = p[0]; *(int4*)&ti[4] = p[1];
        }

        // burst-issue the 8 h-gathers (latency cover); t-gathers issue in-loop
        float hv[8];
        #pragma unroll
        for (int it = 0; it < 8; ++it) hv[it] = ent[hi[it] * DIM + e];

        // online softmax: no sc/tv arrays
        float Z = 0.f, o = 0.f;
        #pragma unroll
        for (int it = 0; it < 8; ++it) {
            float tv = ent[ti[it] * DIM + e];          // issue early, use late
            const char* cb = rt + ri[it] * RELP + e * 16;
            uint2 u0 = *(const uint2*)cb;              // d 0..7
            uint2 u1 = *(const uint2*)(cb + 8);        // d 8..15
            int acc = sdot4(u1.y, ip[3],
                      sdot4(u1.x, ip[2],
                      sdot4(u0.y, ip[1],
                      sdot4(u0.x, ip[0], 0))));
            float sc = dpp_sum16((float)acc * cq * hv[it]);  // item . (R @ h)
            float ex = __expf(sc);                     // scores small: no max pass
            Z += ex;
            o += ex * tv;
        }
        Z += __shfl_xor(Z, 16);
        Z += __shfl_xor(Z, 32);
        o += __shfl_xor(o, 16);
        o += __shfl_xor(o, 32);
        o *= 1.f / Z;

        out_acc += (hop == 0) ? 2.f * o : o;    // faithful: result = o1 + 2*o0

        // item = (item + o) @ W.T ; W row e from LDS
        const float v = item + o;
        float nit = 0.f;
        const float4* wr = (const float4*)&ws[e * WPITCH];
        #pragma unroll
        for (int j = 0; j < 4; ++j) {
            float4 w = wr[j];
            nit += w.x * bcast(v, 4 * j + 0) + w.y * bcast(v, 4 * j + 1)
                 + w.z * bcast(v, 4 * j + 2) + w.w * bcast(v, 4 * j + 3);
        }
        item = nit;
    }

    if (lane < 16) out[n * DIM + e] = out_acc;
}

extern "C" void kernel_launch(void* const* d_in, const int* in_sizes, int n_in,
                              void* d_out, int out_size, void* d_ws, size_t ws_size,
                              hipStream_t stream) {
    const int*   nodes = (const int*)d_in[0];
    const int*   mh    = (const int*)d_in[1];
    const int*   mr    = (const int*)d_in[2];
    const int*   mt    = (const int*)d_in[3];
    const float* ent   = (const float*)d_in[4];
    const float* rel   = (const float*)d_in[5];
    const float* W     = (const float*)d_in[6];
    float*       out   = (float*)d_out;

    dim3 grid(NNODES / 4);   // 1 wave per node, 4 nodes per 256-thread block
    dim3 block(256);
    ripple_kernel<<<grid, block, 0, stream>>>(nodes, mh, mr, mt, ent, rel, W, out);
}

// Round 7
// 100.204 us; speedup vs baseline: 1.2623x; 1.2623x over previous
//
#include <hip/hip_runtime.h>

#define NE     100000
#define NR     64
#define DIM    16
#define NHOP   2
#define NMEM   32
#define NNODES 16384

// Relation table in LDS: f16, transposed (row (r,e) holds column e of R[r],
// i.e. R[r][d][e], d=0..15), packed with ZERO padding (64*256 ushorts = 32 KB)
// and an XOR chunk swizzle for bank-conflict freedom (measured 0 conflicts in
// R2 with identical layout):
//   row (r,e) = 4 chunks of 4 d-values (8 B each); logical chunk c lives at
//   phys slot (c + (e>>2)) & 3.  Read instr j: lane e hits bank
//   8*(e&3) + 2*((j + e>>2)&3) -> 16 lanes pairwise disjoint -> conflict-free.
#define WPITCH 20   // W staging pitch in floats (80 B): 2-way max -> free

typedef __attribute__((ext_vector_type(2))) _Float16 half2_t;

static __device__ __forceinline__ half2_t as_h2(unsigned u) {
    union { unsigned i; half2_t h; } c; c.i = u; return c.h;
}

// q += dot(f16 pair . f16 pair) with fp32 accumulate (v_dot2_f32_f16).
static __device__ __forceinline__ float qdot2(unsigned u, unsigned ip, float q) {
#if __has_builtin(__builtin_amdgcn_fdot2)
    return __builtin_amdgcn_fdot2(as_h2(u), as_h2(ip), q, false);
#else
    half2_t a = as_h2(u), b = as_h2(ip);
    return q + (float)a.x * (float)b.x + (float)a.y * (float)b.y;
#endif
}

// Sum across 16 contiguous lanes, broadcast to all 16. Pure DPP (VALU pipe).
static __device__ __forceinline__ float dpp_sum16(float v) {
    union { int i; float f; } a, b;
    a.f = v;
    b.i = __builtin_amdgcn_update_dpp(0, a.i, 0xB1,  0xf, 0xf, true); a.f += b.f; // quad_perm [1,0,3,2]
    b.i = __builtin_amdgcn_update_dpp(0, a.i, 0x4E,  0xf, 0xf, true); a.f += b.f; // quad_perm [2,3,0,1]
    b.i = __builtin_amdgcn_update_dpp(0, a.i, 0x124, 0xf, 0xf, true); a.f += b.f; // row_ror:4
    b.i = __builtin_amdgcn_update_dpp(0, a.i, 0x128, 0xf, 0xf, true); a.f += b.f; // row_ror:8
    return a.f;
}

// Wave-uniform broadcast into an SGPR.
static __device__ __forceinline__ float bcast(float v, int l) {
    return __int_as_float(__builtin_amdgcn_readlane(__float_as_int(v), l));
}

// float -> f16 bits, RNE
static __device__ __forceinline__ unsigned short f2h(float f) {
    union { _Float16 h; unsigned short s; } c; c.h = (_Float16)f; return c.s;
}
// pack two floats -> 2 x f16 in one dword
static __device__ __forceinline__ unsigned pack2h(float a, float b) {
    union { _Float16 h[2]; unsigned u; } c;
    c.h[0] = (_Float16)a; c.h[1] = (_Float16)b;
    return c.u;
}

// ---- Prep: entity_emb fp32 -> f16 table in d_ws (6.4 MB -> 3.2 MB, L2-resident)
extern "C" __global__ void __launch_bounds__(256)
ent_quant_kernel(const float* __restrict__ ent, _Float16* __restrict__ et, int n4) {
    int i = blockIdx.x * 256 + threadIdx.x;
    if (i < n4) {
        float4 v = ((const float4*)ent)[i];
        union { _Float16 h[4]; unsigned long long u; } c;
        c.h[0] = (_Float16)v.x; c.h[1] = (_Float16)v.y;
        c.h[2] = (_Float16)v.z; c.h[3] = (_Float16)v.w;
        *(unsigned long long*)(et + 4 * (long long)i) = c.u;
    }
}

extern "C" __global__ void __launch_bounds__(512, 8)
ripple_kernel(const int* __restrict__ nodes,
              const int* __restrict__ mh,
              const int* __restrict__ mr,
              const int* __restrict__ mt,
              const _Float16* __restrict__ et,
              const float* __restrict__ rel,
              const float* __restrict__ W,
              float* __restrict__ out)
{
    __shared__ __align__(16) unsigned short rt[NR * 256];   // 32768 B
    __shared__ __align__(16) float ws[DIM * WPITCH];        // 1280 B

    const int tid = threadIdx.x;

    // ---- Stage relation_emb (64 x 256 fp32) transposed+f16+swizzled ----
    {
        const float4* rel4 = (const float4*)rel;
        #pragma unroll
        for (int i = 0; i < 8; ++i) {
            int vidx = i * 512 + tid;            // 4096 float4s total
            float4 v = rel4[vidx];
            int k0 = vidx * 4;                   // flat fp32 index
            int r  = k0 >> 8;
            int k  = k0 & 255;
            int d  = k >> 4;
            int e0 = k & 15;                     // e0 % 4 == 0 -> shares e>>2
            int phys = ((d >> 2) + (e0 >> 2)) & 3;
            unsigned short* p = &rt[r * 256 + e0 * 16 + phys * 4 + (d & 3)];
            p[0]  = f2h(v.x);
            p[16] = f2h(v.y);
            p[32] = f2h(v.z);
            p[48] = f2h(v.w);
        }
        if (tid < 256) ws[(tid >> 4) * WPITCH + (tid & 15)] = W[tid];
    }
    __syncthreads();

    const int lane = tid & 63;
    const int wid  = tid >> 6;
    const int g    = lane >> 4;   // mem-group 0..3 -> owns mems [8g, 8g+8)
    const int e    = lane & 15;   // dim index
    const int n    = blockIdx.x * 8 + wid;

    // Per-lane byte offsets into a relation's row for logical chunk j (swizzled)
    int voff[4];
    {
        const int s = e >> 2;
        #pragma unroll
        for (int j = 0; j < 4; ++j)
            voff[j] = e * 32 + (((j + s) & 3) << 3);
    }

    float item    = (float)et[nodes[n] * DIM + e];
    float out_acc = 0.f;

    #pragma unroll
    for (int hop = 0; hop < NHOP; ++hop) {
        // item vector -> 8 packed f16 pairs, wave-uniform (SGPRs)
        unsigned ip[8];
        #pragma unroll
        for (int j = 0; j < 8; ++j)
            ip[j] = pack2h(bcast(item, 2 * j), bcast(item, 2 * j + 1));

        // contiguous per-lane index loads: 6 x int4
        const int ibase = hop * (NNODES * NMEM) + n * NMEM + g * 8;
        int hi[8], ri[8], ti[8];
        {
            const int4* p;
            p = (const int4*)(mh + ibase); *(int4*)&hi[0] = p[0]; *(int4*)&hi[4] = p[1];
            p = (const int4*)(mr + ibase); *(int4*)&ri[0] = p[0]; *(int4*)&ri[4] = p[1];
            p = (const int4*)(mt + ibase); *(int4*)&ti[0] = p[0]; *(int4*)&ti[4] = p[1];
        }

        // burst-issue the 8 h-gathers (f16, 32 B per 16-lane group, L2-hot)
        float hv[8];
        #pragma unroll
        for (int it = 0; it < 8; ++it) hv[it] = (float)et[hi[it] * DIM + e];

        // online softmax: no sc/tv arrays
        float Z = 0.f, o = 0.f;
        #pragma unroll
        for (int it = 0; it < 8; ++it) {
            float tv = (float)et[ti[it] * DIM + e];   // issue early, use late
            const char* rbase = (const char*)rt + (ri[it] << 9);
            float q = 0.f;
            #pragma unroll
            for (int j = 0; j < 4; ++j) {
                uint2 u = *(const uint2*)(rbase + voff[j]);
                q = qdot2(u.x, ip[2 * j + 0], q);
                q = qdot2(u.y, ip[2 * j + 1], q);
            }
            float sc = dpp_sum16(q * hv[it]);         // item . (R @ h)
            float ex = __expf(sc);                    // scores small: no max pass
            Z += ex;
            o += ex * tv;
        }
        Z += __shfl_xor(Z, 16);
        Z += __shfl_xor(Z, 32);
        o += __shfl_xor(o, 16);
        o += __shfl_xor(o, 32);
        o *= 1.f / Z;

        out_acc += (hop == 0) ? 2.f * o : o;          // faithful: o1 + 2*o0

        // item = (item + o) @ W.T ; W row e from LDS
        const float v = item + o;
        float nit = 0.f;
        const float4* wr = (const float4*)&ws[e * WPITCH];
        #pragma unroll
        for (int j = 0; j < 4; ++j) {
            float4 w = wr[j];
            nit += w.x * bcast(v, 4 * j + 0) + w.y * bcast(v, 4 * j + 1)
                 + w.z * bcast(v, 4 * j + 2) + w.w * bcast(v, 4 * j + 3);
        }
        item = nit;
    }

    if (lane < 16) out[n * DIM + e] = out_acc;
}

extern "C" void kernel_launch(void* const* d_in, const int* in_sizes, int n_in,
                              void* d_out, int out_size, void* d_ws, size_t ws_size,
                              hipStream_t stream) {
    const int*   nodes = (const int*)d_in[0];
    const int*   mh    = (const int*)d_in[1];
    const int*   mr    = (const int*)d_in[2];
    const int*   mt    = (const int*)d_in[3];
    const float* ent   = (const float*)d_in[4];
    const float* rel   = (const float*)d_in[5];
    const float* W     = (const float*)d_in[6];
    float*       out   = (float*)d_out;
    _Float16*    et    = (_Float16*)d_ws;     // 3.2 MB f16 entity table

    const int n4 = NE * DIM / 4;              // 400000 float4s
    ent_quant_kernel<<<(n4 + 255) / 256, 256, 0, stream>>>(ent, et, n4);

    dim3 grid(NNODES / 8);   // 1 wave per node, 8 nodes per 512-thread block
    dim3 block(512);
    ripple_kernel<<<grid, block, 0, stream>>>(nodes, mh, mr, mt, et, rel, W, out);
}

// Round 8
// 100.004 us; speedup vs baseline: 1.2648x; 1.0020x over previous
//
#include <hip/hip_runtime.h>

#define NE     100000
#define NR     64
#define DIM    16
#define NHOP   2
#define NMEM   32
#define NNODES 16384

#define WPITCH 20                 // W staging pitch in floats (80 B)
#define ET_BYTES (NE * DIM * 2)   // 3.2 MB f16 entity table in d_ws
#define NB_ET  ((NE * DIM / 4 + 255) / 256)   // 1563 blocks for et conversion

typedef __attribute__((ext_vector_type(2))) _Float16 half2_t;

static __device__ __forceinline__ half2_t as_h2(unsigned u) {
    union { unsigned i; half2_t h; } c; c.i = u; return c.h;
}
static __device__ __forceinline__ float qdot2(unsigned u, unsigned ip, float q) {
#if __has_builtin(__builtin_amdgcn_fdot2)
    return __builtin_amdgcn_fdot2(as_h2(u), as_h2(ip), q, false);
#else
    half2_t a = as_h2(u), b = as_h2(ip);
    return q + (float)a.x * (float)b.x + (float)a.y * (float)b.y;
#endif
}
static __device__ __forceinline__ float dpp_sum16(float v) {
    union { int i; float f; } a, b;
    a.f = v;
    b.i = __builtin_amdgcn_update_dpp(0, a.i, 0xB1,  0xf, 0xf, true); a.f += b.f; // quad_perm [1,0,3,2]
    b.i = __builtin_amdgcn_update_dpp(0, a.i, 0x4E,  0xf, 0xf, true); a.f += b.f; // quad_perm [2,3,0,1]
    b.i = __builtin_amdgcn_update_dpp(0, a.i, 0x124, 0xf, 0xf, true); a.f += b.f; // row_ror:4
    b.i = __builtin_amdgcn_update_dpp(0, a.i, 0x128, 0xf, 0xf, true); a.f += b.f; // row_ror:8
    return a.f;
}
static __device__ __forceinline__ float bcast(float v, int l) {
    return __int_as_float(__builtin_amdgcn_readlane(__float_as_int(v), l));
}
static __device__ __forceinline__ unsigned short f2h(float f) {
    union { _Float16 h; unsigned short s; } c; c.h = (_Float16)f; return c.s;
}
static __device__ __forceinline__ unsigned pack2h(float a, float b) {
    union { _Float16 h[2]; unsigned u; } c;
    c.h[0] = (_Float16)a; c.h[1] = (_Float16)b;
    return c.u;
}

// ---- Prep: (a) entity_emb fp32 -> f16 table; (b) relation_emb fp32 ->
// f16 TRANSPOSED + XOR-swizzled table (exact byte layout the main kernel
// copies flat into LDS; swizzle details as R2/R7, measured 0 conflicts).
extern "C" __global__ void __launch_bounds__(256)
prep_kernel(const float* __restrict__ ent, const float* __restrict__ rel,
            _Float16* __restrict__ et, unsigned short* __restrict__ rtg, int n4)
{
    const int b = blockIdx.x, tid = threadIdx.x;
    if (b < NB_ET) {
        int i = b * 256 + tid;
        if (i < n4) {
            float4 v = ((const float4*)ent)[i];
            union { _Float16 h[4]; unsigned long long u; } c;
            c.h[0] = (_Float16)v.x; c.h[1] = (_Float16)v.y;
            c.h[2] = (_Float16)v.z; c.h[3] = (_Float16)v.w;
            *(unsigned long long*)(et + 4 * (long long)i) = c.u;
        }
    } else {
        int j = (b - NB_ET) * 256 + tid;          // 0..1023
        const float4* rel4 = (const float4*)rel;
        #pragma unroll
        for (int k = 0; k < 4; ++k) {
            int vidx = k * 1024 + j;              // 4096 float4s total
            float4 v = rel4[vidx];
            int k0 = vidx * 4;
            int r  = k0 >> 8;
            int kk = k0 & 255;
            int d  = kk >> 4;
            int e0 = kk & 15;
            int phys = ((d >> 2) + (e0 >> 2)) & 3;
            unsigned short* p = &rtg[r * 256 + e0 * 16 + phys * 4 + (d & 3)];
            p[0]  = f2h(v.x);
            p[16] = f2h(v.y);
            p[32] = f2h(v.z);
            p[48] = f2h(v.w);
        }
    }
}

extern "C" __global__ void __launch_bounds__(256, 4)
ripple_kernel(const int* __restrict__ nodes,
              const int* __restrict__ mh,
              const int* __restrict__ mr,
              const int* __restrict__ mt,
              const _Float16* __restrict__ et,
              const unsigned short* __restrict__ rtg,
              const float* __restrict__ W,
              float* __restrict__ out)
{
    __shared__ __align__(16) unsigned short rt[NR * 256];   // 32768 B
    __shared__ __align__(16) float ws[DIM * WPITCH];        // 1280 B

    const int tid  = threadIdx.x;
    const int lane = tid & 63;
    const int wid  = tid >> 6;
    const int g    = lane >> 4;   // mem-group 0..3 -> owns mems [8g, 8g+8)
    const int e    = lane & 15;   // dim index
    const int n    = blockIdx.x * 4 + wid;

    // ---- Round 1: all index loads (both hops) — issue first ----
    const int ib0 = 0 * (NNODES * NMEM) + n * NMEM + g * 8;
    const int ib1 = 1 * (NNODES * NMEM) + n * NMEM + g * 8;
    int hi0[8], ri0[8], ti0[8], hi1[8], ri1[8], ti1[8];
    {
        const int4* p;
        p = (const int4*)(mh + ib0); *(int4*)&hi0[0] = p[0]; *(int4*)&hi0[4] = p[1];
        p = (const int4*)(mr + ib0); *(int4*)&ri0[0] = p[0]; *(int4*)&ri0[4] = p[1];
        p = (const int4*)(mt + ib0); *(int4*)&ti0[0] = p[0]; *(int4*)&ti0[4] = p[1];
        p = (const int4*)(mh + ib1); *(int4*)&hi1[0] = p[0]; *(int4*)&hi1[4] = p[1];
        p = (const int4*)(mr + ib1); *(int4*)&ri1[0] = p[0]; *(int4*)&ri1[4] = p[1];
        p = (const int4*)(mt + ib1); *(int4*)&ti1[0] = p[0]; *(int4*)&ti1[4] = p[1];
    }
    const int nd = nodes[n];

    // ---- Independent staging loads (issue while indices are in flight) ----
    float4 stg[8];
    {
        const float4* src = (const float4*)rtg;
        #pragma unroll
        for (int i = 0; i < 8; ++i) stg[i] = src[i * 256 + tid];
    }
    const float wv = W[tid];

    // ---- Round 2: all entity gathers (both hops), burst-issued ----
    float item = (float)et[nd * DIM + e];
    float hv0[8], tv0[8], hv1[8], tv1[8];
    #pragma unroll
    for (int it = 0; it < 8; ++it) {
        hv0[it] = (float)et[hi0[it] * DIM + e];
        tv0[it] = (float)et[ti0[it] * DIM + e];
        hv1[it] = (float)et[hi1[it] * DIM + e];
        tv1[it] = (float)et[ti1[it] * DIM + e];
    }

    // ---- LDS fill (vmcnt FIFO: waits staging loads, NOT the gathers) ----
    {
        float4* dst = (float4*)rt;
        #pragma unroll
        for (int i = 0; i < 8; ++i) dst[i * 256 + tid] = stg[i];
        ws[(tid >> 4) * WPITCH + (tid & 15)] = wv;
    }
    __syncthreads();

    // Per-lane byte offsets into a relation's row for logical chunk j (swizzled)
    int voff[4];
    {
        const int s = e >> 2;
        #pragma unroll
        for (int j = 0; j < 4; ++j)
            voff[j] = e * 32 + (((j + s) & 3) << 3);
    }

    float out_acc = 0.f;

    #pragma unroll
    for (int hop = 0; hop < NHOP; ++hop) {
        const int*   ri = hop ? ri1 : ri0;
        const float* hv = hop ? hv1 : hv0;
        const float* tv = hop ? tv1 : tv0;

        // item vector -> 8 packed f16 pairs, wave-uniform (SGPRs)
        unsigned ip[8];
        #pragma unroll
        for (int j = 0; j < 8; ++j)
            ip[j] = pack2h(bcast(item, 2 * j), bcast(item, 2 * j + 1));

        // online softmax over the 8 owned memories
        float Z = 0.f, o = 0.f;
        #pragma unroll
        for (int it = 0; it < 8; ++it) {
            const char* rbase = (const char*)rt + (ri[it] << 9);
            float q = 0.f;
            #pragma unroll
            for (int j = 0; j < 4; ++j) {
                uint2 u = *(const uint2*)(rbase + voff[j]);
                q = qdot2(u.x, ip[2 * j + 0], q);
                q = qdot2(u.y, ip[2 * j + 1], q);
            }
            float sc = dpp_sum16(q * hv[it]);   // item . (R @ h)
            float ex = __expf(sc);              // scores small: no max pass
            Z += ex;
            o += ex * tv[it];
        }
        Z += __shfl_xor(Z, 16);
        Z += __shfl_xor(Z, 32);
        o += __shfl_xor(o, 16);
        o += __shfl_xor(o, 32);
        o *= 1.f / Z;

        out_acc += (hop == 0) ? 2.f * o : o;    // faithful: result = o1 + 2*o0

        // item = (item + o) @ W.T ; W row e from LDS
        const float v = item + o;
        float nit = 0.f;
        const float4* wr = (const float4*)&ws[e * WPITCH];
        #pragma unroll
        for (int j = 0; j < 4; ++j) {
            float4 w = wr[j];
            nit += w.x * bcast(v, 4 * j + 0) + w.y * bcast(v, 4 * j + 1)
                 + w.z * bcast(v, 4 * j + 2) + w.w * bcast(v, 4 * j + 3);
        }
        item = nit;
    }

    if (lane < 16) out[n * DIM + e] = out_acc;
}

extern "C" void kernel_launch(void* const* d_in, const int* in_sizes, int n_in,
                              void* d_out, int out_size, void* d_ws, size_t ws_size,
                              hipStream_t stream) {
    const int*   nodes = (const int*)d_in[0];
    const int*   mh    = (const int*)d_in[1];
    const int*   mr    = (const int*)d_in[2];
    const int*   mt    = (const int*)d_in[3];
    const float* ent   = (const float*)d_in[4];
    const float* rel   = (const float*)d_in[5];
    const float* W     = (const float*)d_in[6];
    float*       out   = (float*)d_out;

    _Float16*       et  = (_Float16*)d_ws;                       // 3.2 MB
    unsigned short* rtg = (unsigned short*)((char*)d_ws + ET_BYTES); // 32 KB

    const int n4 = NE * DIM / 4;              // 400000 float4s
    prep_kernel<<<NB_ET + 4, 256, 0, stream>>>(ent, rel, et, rtg, n4);

    dim3 grid(NNODES / 4);   // 1 wave per node, 4 nodes per 256-thread block
    dim3 block(256);
    ripple_kernel<<<grid, block, 0, stream>>>(nodes, mh, mr, mt, et, rtg, W, out);
}